// Round 6
// baseline (140.923 us; speedup 1.0000x reference)
//
#include <hip/hip_runtime.h>
#include <stdint.h>

#define Bd 4
#define Nn 48
#define Mm 48
#define Hh 192
#define Ww 640
#define HW (Hh*Ww)              // 122880 pixels per mask
#define WORDS (HW/64)           // 1920 uint64 words per mask
#define TILE_PX 4096            // per block-iteration; HW % 4096 == 0 -> tile never straddles masks
#define TILES_A ((Bd*Nn*HW)/TILE_PX)      // 5760
#define TILES_TOTAL (2*TILES_A)           // 11520

typedef float f4v __attribute__((ext_vector_type(4)));

__device__ __forceinline__ unsigned int wave_sum(unsigned int s) {
    #pragma unroll
    for (int off = 32; off; off >>= 1) s += __shfl_down(s, off);
    return s;
}

// ---------------------------------------------------------------------------
// K1: pack fp32 binary masks -> bitmask words + fused per-mask popcount sums.
// Persistent grid (2048 blocks), grid-stride over 4096-px tiles. Lane owns 16
// consecutive px (4x float4). NONTEMPORAL loads: input is read exactly once,
// so bypass L3 retention and stream from HBM (R2-R5 showed ~half the stream
// was L3-served at a blended ~2.8 TB/s; testing whether nt unblocks it).
// Packed output stored normally (read 3x by later kernels -> want it cached).
// One wave-reduce + atomicAdd per wave-iteration (proven free in R3).
// ---------------------------------------------------------------------------
__global__ void pack_kernel(const float* __restrict__ a, const float* __restrict__ b,
                            ushort* __restrict__ packA, ushort* __restrict__ packB,
                            unsigned int* __restrict__ saInt, unsigned int* __restrict__ sbInt) {
    const int wid = threadIdx.x >> 6, lane = threadIdx.x & 63;
    for (int tile = blockIdx.x; tile < TILES_TOTAL; tile += gridDim.x) {
        const float* src; ushort* dst; unsigned int* cnt; int rel;
        if (tile < TILES_A) { src = a; dst = packA; cnt = saInt; rel = tile; }
        else                { src = b; dst = packB; cnt = sbInt; rel = tile - TILES_A; }
        const long long px = (long long)rel * TILE_PX + wid * 1024 + lane * 16;
        const f4v* f = reinterpret_cast<const f4v*>(src + px);
        f4v v0 = __builtin_nontemporal_load(f + 0);
        f4v v1 = __builtin_nontemporal_load(f + 1);
        f4v v2 = __builtin_nontemporal_load(f + 2);
        f4v v3 = __builtin_nontemporal_load(f + 3);
        unsigned int bits =
              (v0[0] > 0.0f ? 1u       : 0u) | (v0[1] > 0.0f ? 1u << 1  : 0u)
            | (v0[2] > 0.0f ? 1u << 2  : 0u) | (v0[3] > 0.0f ? 1u << 3  : 0u)
            | (v1[0] > 0.0f ? 1u << 4  : 0u) | (v1[1] > 0.0f ? 1u << 5  : 0u)
            | (v1[2] > 0.0f ? 1u << 6  : 0u) | (v1[3] > 0.0f ? 1u << 7  : 0u)
            | (v2[0] > 0.0f ? 1u << 8  : 0u) | (v2[1] > 0.0f ? 1u << 9  : 0u)
            | (v2[2] > 0.0f ? 1u << 10 : 0u) | (v2[3] > 0.0f ? 1u << 11 : 0u)
            | (v3[0] > 0.0f ? 1u << 12 : 0u) | (v3[1] > 0.0f ? 1u << 13 : 0u)
            | (v3[2] > 0.0f ? 1u << 14 : 0u) | (v3[3] > 0.0f ? 1u << 15 : 0u);
        dst[px >> 4] = (ushort)bits;          // 128B contiguous per wave
        unsigned int s = wave_sum(__popc(bits));
        if (lane == 0) atomicAdd(&cnt[(int)(px / HW)], s);   // ~30 adds/counter
    }
}

// ---------------------------------------------------------------------------
// K2 (reverted to R3 design — 9216 waves, L2-resident, measured fast):
// one wave per (b,n,m) pair; inter = sum popcount(A&B); float32 q-test
// exactly as the reference; set bit m of qmask[b][n] when qualifying.
// ---------------------------------------------------------------------------
__global__ void pair_kernel(const uint64_t* __restrict__ packA, const uint64_t* __restrict__ packB,
                            const unsigned int* __restrict__ saInt, const unsigned int* __restrict__ sbInt,
                            unsigned long long* __restrict__ qmask) {
    int wave = blockIdx.x * (blockDim.x >> 6) + (threadIdx.x >> 6);
    int lane = threadIdx.x & 63;
    int bb = wave / (Nn * Mm);
    int nm = wave % (Nn * Mm);
    int n = nm / Mm, m = nm % Mm;
    const uint64_t* A  = packA + (size_t)(bb * Nn + n) * WORDS;
    const uint64_t* Bp = packB + (size_t)(bb * Mm + m) * WORDS;
    unsigned int s = 0;
    #pragma unroll 5
    for (int w = lane; w < WORDS; w += 64)
        s += (unsigned int)__popcll(A[w] & Bp[w]);
    s = wave_sum(s);
    if (lane == 0) {
        float inter = (float)s;
        float un = (float)saInt[bb * Nn + n] + (float)sbInt[bb * Mm + m] - inter;
        if (inter / fmaxf(un, 1.0f) > 0.8f)
            atomicOr(&qmask[bb * Nn + n], 1ull << m);
    }
}

// ---------------------------------------------------------------------------
// K3+K4 fused: per word, OR of (a_n ^ b_m) over qualifying pairs -> LDS ->
// coalesced float4 expansion to the output.
// ---------------------------------------------------------------------------
__global__ void words_expand_kernel(const uint64_t* __restrict__ packA,
                                    const uint64_t* __restrict__ packB,
                                    const unsigned long long* __restrict__ qmask,
                                    float* __restrict__ out) {
    __shared__ uint64_t sw[256];
    const int t = threadIdx.x;
    const int i = blockIdx.x * 256 + t;       // word index in [0, Bd*WORDS)
    const int bb = i / WORDS, w = i % WORDS;
    uint64_t acc = 0;
    for (int n = 0; n < Nn; ++n) {
        unsigned long long qm = qmask[bb * Nn + n];
        if (!qm) continue;
        uint64_t aw = packA[(size_t)(bb * Nn + n) * WORDS + w];
        while (qm) {
            int m = __ffsll((long long)qm) - 1;
            qm &= qm - 1;
            acc |= aw ^ packB[(size_t)(bb * Mm + m) * WORDS + w];
        }
        if (acc == ~0ull) break;              // word fully covered
    }
    sw[t] = acc;
    __syncthreads();
    float4* out4 = reinterpret_cast<float4*>(out) + (size_t)blockIdx.x * 4096;
    #pragma unroll
    for (int k = 0; k < 16; ++k) {
        int p0 = k * 1024 + 4 * t;
        uint64_t wv = sw[p0 >> 6];
        unsigned int bits = (unsigned int)(wv >> (p0 & 63)) & 0xFu;
        float4 f;
        f.x = (bits & 1u) ? 0.0f : 1.0f;
        f.y = (bits & 2u) ? 0.0f : 1.0f;
        f.z = (bits & 4u) ? 0.0f : 1.0f;
        f.w = (bits & 8u) ? 0.0f : 1.0f;
        out4[k * 256 + t] = f;
    }
}

extern "C" void kernel_launch(void* const* d_in, const int* in_sizes, int n_in,
                              void* d_out, int out_size, void* d_ws, size_t ws_size,
                              hipStream_t stream) {
    const float* a = (const float*)d_in[0];   // stereo_warped_target  [B,N,H,W]
    const float* b = (const float*)d_in[1];   // temporal_warped_target [B,M,H,W]
    float* out = (float*)d_out;               // [B,1,H,W]

    uint8_t* ws = (uint8_t*)d_ws;
    const size_t szPack = (size_t)Bd * Nn * WORDS * sizeof(uint64_t);  // 2.95 MB each
    uint64_t* packA = (uint64_t*)(ws);
    uint64_t* packB = (uint64_t*)(ws + szPack);
    // zero-initialized region: saInt | sbInt | qmask (contiguous)
    unsigned int* saInt = (unsigned int*)(ws + 2 * szPack);            // 192 u32
    unsigned int* sbInt = saInt + Bd * Nn;                             // 192 u32
    unsigned long long* qmask = (unsigned long long*)(sbInt + Bd * Mm);// 192 u64
    const size_t zeroBytes = (size_t)Bd * (Nn + Mm) * 4 + (size_t)Bd * Nn * 8;

    hipMemsetAsync(saInt, 0, zeroBytes, stream);

    // K1: pack + popcount sums (persistent grid, nt loads)
    pack_kernel<<<2048, 256, 0, stream>>>(a, b, (ushort*)packA, (ushort*)packB, saInt, sbInt);

    // K2: per-pair IoU -> qmask (9216 waves, 4 per block)
    pair_kernel<<<(Bd * Nn * Mm) / 4, 256, 0, stream>>>(packA, packB, saInt, sbInt, qmask);

    // K3+K4 fused: zero-words + float expansion
    words_expand_kernel<<<(Bd * WORDS) / 256, 256, 0, stream>>>(packA, packB, qmask, out);
}

// Round 8
// 67.057 us; speedup vs baseline: 2.1015x; 2.1015x over previous
//
#include <hip/hip_runtime.h>
#include <stdint.h>

#define Bd 4
#define Nn 48
#define Mm 48
#define HW (192*640)            // 122880 px per mask
#define WORDS (HW/64)           // 1920 uint64 words per mask
#define PIX_PER_BLOCK 4096      // 256 threads x 16 px; HW % 4096 == 0
#define ITERS 4                 // float4 loads per thread
#define OUTWORDS (Bd*WORDS)     // 7680

// ---------------------------------------------------------------------------
// K1: pack fp32 binary masks -> uint64 bit words. R3's measured-best shape
// (coalesced float4 -> nibble -> padded LDS -> 64-lane uint64 assembly),
// atomic popcount tail removed (sa/sb moved into K2). Pure stream, no memset
// dependency, nothing read-before-write.
// ---------------------------------------------------------------------------
__global__ void pack_kernel(const float* __restrict__ a, const float* __restrict__ b,
                            uint64_t* __restrict__ packA, uint64_t* __restrict__ packB) {
    __shared__ unsigned int nib[ITERS * 256 + (ITERS * 256) / 16];  // padded idx + idx/16
    const int blocksA = (Bd * Nn * HW) / PIX_PER_BLOCK;   // 5760
    long long pixBase;
    const float* src; uint64_t* dst;
    if (blockIdx.x < blocksA) {
        src = a; dst = packA;
        pixBase = (long long)blockIdx.x * PIX_PER_BLOCK;
    } else {
        src = b; dst = packB;
        pixBase = (long long)(blockIdx.x - blocksA) * PIX_PER_BLOCK;
    }
    const float4* s4 = reinterpret_cast<const float4*>(src) + (pixBase >> 2);
    const int t = threadIdx.x;
    #pragma unroll
    for (int c = 0; c < ITERS; ++c) {
        float4 v = s4[c * 256 + t];                       // fully coalesced 16B/lane
        unsigned int n = (v.x > 0.0f ? 1u : 0u) | (v.y > 0.0f ? 2u : 0u)
                       | (v.z > 0.0f ? 4u : 0u) | (v.w > 0.0f ? 8u : 0u);
        int idx = c * 256 + t;
        nib[idx + (idx >> 4)] = n;
    }
    __syncthreads();
    if (t < 64) {
        uint64_t word = 0;
        #pragma unroll
        for (int k = 0; k < 16; ++k)
            word |= (uint64_t)nib[17 * t + k] << (4 * k);
        dst[(pixBase >> 6) + t] = word;                   // 512B contiguous per block
    }
}

__device__ __forceinline__ unsigned int wave_sum(unsigned int s) {
    #pragma unroll
    for (int off = 32; off; off >>= 1) s += __shfl_down(s, off);
    return s;
}

// ---------------------------------------------------------------------------
// K2: 2x2-tiled pairwise IoU. One wave per (b, 2 n-rows, 2 m-rows): 4 loads,
// 4 intersections + 4 row popcounts per word (sa/sb inline -> no pack atomics,
// no memset). L2 traffic 283 -> 138 MB vs per-pair design. q-test in float32
// exactly as the reference (counts are exact ints < 2^24); result stored as
// one byte per pair (plain store, every entry written -> re-poison safe).
// ---------------------------------------------------------------------------
__global__ void pair_kernel(const uint64_t* __restrict__ packA, const uint64_t* __restrict__ packB,
                            unsigned char* __restrict__ q) {
    const int wave = blockIdx.x * 4 + (threadIdx.x >> 6);  // 0..2303
    const int lane = threadIdx.x & 63;
    const int bb = wave / 576;
    const int r  = wave % 576;
    const int ni = (r / 24) * 2, mi = (r % 24) * 2;
    const uint64_t* A0 = packA + ((size_t)bb * Nn + ni) * WORDS;
    const uint64_t* A1 = A0 + WORDS;
    const uint64_t* B0 = packB + ((size_t)bb * Mm + mi) * WORDS;
    const uint64_t* B1 = B0 + WORDS;
    unsigned int i00 = 0, i01 = 0, i10 = 0, i11 = 0, pa0 = 0, pa1 = 0, pb0 = 0, pb1 = 0;
    #pragma unroll 5
    for (int w = lane; w < WORDS; w += 64) {
        uint64_t a0 = A0[w], a1 = A1[w], b0 = B0[w], b1 = B1[w];
        i00 += (unsigned int)__popcll(a0 & b0);
        i01 += (unsigned int)__popcll(a0 & b1);
        i10 += (unsigned int)__popcll(a1 & b0);
        i11 += (unsigned int)__popcll(a1 & b1);
        pa0 += (unsigned int)__popcll(a0);
        pa1 += (unsigned int)__popcll(a1);
        pb0 += (unsigned int)__popcll(b0);
        pb1 += (unsigned int)__popcll(b1);
    }
    i00 = wave_sum(i00); i01 = wave_sum(i01); i10 = wave_sum(i10); i11 = wave_sum(i11);
    pa0 = wave_sum(pa0); pa1 = wave_sum(pa1); pb0 = wave_sum(pb0); pb1 = wave_sum(pb1);
    if (lane == 0) {
        float fa0 = (float)pa0, fa1 = (float)pa1, fb0 = (float)pb0, fb1 = (float)pb1;
        unsigned char q00 = ((float)i00 / fmaxf(fa0 + fb0 - (float)i00, 1.0f)) > 0.8f;
        unsigned char q01 = ((float)i01 / fmaxf(fa0 + fb1 - (float)i01, 1.0f)) > 0.8f;
        unsigned char q10 = ((float)i10 / fmaxf(fa1 + fb0 - (float)i10, 1.0f)) > 0.8f;
        unsigned char q11 = ((float)i11 / fmaxf(fa1 + fb1 - (float)i11, 1.0f)) > 0.8f;
        const size_t base = ((size_t)bb * Nn + ni) * Mm + mi;
        q[base] = q00; q[base + 1] = q01;
        q[base + Mm] = q10; q[base + Mm + 1] = q11;
    }
}

// ---------------------------------------------------------------------------
// K3: per output word, OR of (a_n ^ b_m) over qualifying pairs, then coalesced
// float4 expansion. 120 one-wave blocks x 64 words (64 | WORDS -> no batch
// straddle). q-bit row masks rebuilt in LDS from the byte array.
// ---------------------------------------------------------------------------
__global__ void words_expand_kernel(const uint64_t* __restrict__ packA,
                                    const uint64_t* __restrict__ packB,
                                    const unsigned char* __restrict__ q,
                                    float* __restrict__ out) {
    __shared__ uint64_t sw[64];
    __shared__ uint64_t qm[Nn];
    const int t = threadIdx.x;                 // 0..63
    const int base = blockIdx.x * 64;          // global word index base
    const int bb = base / WORDS;
    if (t < Nn) {
        const unsigned int* qrow = reinterpret_cast<const unsigned int*>(q + ((size_t)bb * Nn + t) * Mm);
        uint64_t m = 0;
        #pragma unroll
        for (int k = 0; k < 12; ++k) {
            unsigned int v = qrow[k];          // 4 bytes (0/1) -> 4 bits
            m |= (uint64_t)((v & 1u) | ((v >> 7) & 2u) | ((v >> 14) & 4u) | ((v >> 21) & 8u)) << (4 * k);
        }
        qm[t] = m;
    }
    __syncthreads();
    const int w = (base % WORDS) + t;          // word within this batch's rows
    uint64_t acc = 0;
    for (int n = 0; n < Nn; ++n) {
        uint64_t qmn = qm[n];
        if (!qmn) continue;
        uint64_t aw = packA[((size_t)bb * Nn + n) * WORDS + w];
        while (qmn) {
            int m = __ffsll((long long)qmn) - 1;
            qmn &= qmn - 1;
            acc |= aw ^ packB[((size_t)bb * Mm + m) * WORDS + w];
        }
        if (acc == ~0ull) break;               // word fully covered
    }
    sw[t] = acc;
    __syncthreads();
    float4* out4 = reinterpret_cast<float4*>(out) + (size_t)blockIdx.x * 1024;
    #pragma unroll
    for (int k = 0; k < 16; ++k) {
        int j = k * 64 + t;                    // float4 index within block [0,1024)
        unsigned int bits = (unsigned int)(sw[j >> 4] >> ((4 * j) & 63)) & 0xFu;
        float4 f;
        f.x = (bits & 1u) ? 0.0f : 1.0f;
        f.y = (bits & 2u) ? 0.0f : 1.0f;
        f.z = (bits & 4u) ? 0.0f : 1.0f;
        f.w = (bits & 8u) ? 0.0f : 1.0f;
        out4[j] = f;
    }
}

extern "C" void kernel_launch(void* const* d_in, const int* in_sizes, int n_in,
                              void* d_out, int out_size, void* d_ws, size_t ws_size,
                              hipStream_t stream) {
    const float* a = (const float*)d_in[0];   // stereo_warped_target  [B,N,H,W]
    const float* b = (const float*)d_in[1];   // temporal_warped_target [B,M,H,W]
    float* out = (float*)d_out;               // [B,1,H,W]

    uint8_t* ws = (uint8_t*)d_ws;
    const size_t szPack = (size_t)Bd * Nn * WORDS * sizeof(uint64_t);  // 2.95 MB each
    uint64_t* packA = (uint64_t*)ws;
    uint64_t* packB = (uint64_t*)(ws + szPack);
    unsigned char* q = (unsigned char*)(ws + 2 * szPack);              // 9216 bytes

    // K1: pack (11520 blocks)
    pack_kernel<<<(Bd * (Nn + Mm) * HW) / PIX_PER_BLOCK, 256, 0, stream>>>(a, b, packA, packB);

    // K2: 2x2-tiled pair IoU -> q bytes (576 blocks)
    pair_kernel<<<(Bd * 24 * 24) / 4, 256, 0, stream>>>(packA, packB, q);

    // K3: zero-words + float expansion (120 one-wave blocks)
    words_expand_kernel<<<OUTWORDS / 64, 64, 0, stream>>>(packA, packB, q, out);
}

// Round 9
// 67.023 us; speedup vs baseline: 2.1026x; 1.0005x over previous
//
#include <hip/hip_runtime.h>
#include <stdint.h>

#define Bd 4
#define Nn 48
#define Mm 48
#define HW (192*640)            // 122880 px per mask
#define WORDS (HW/64)           // 1920 uint64 words per mask
#define PIX_PER_BLOCK 4096      // 256 threads; HW % 4096 == 0 -> block never straddles masks
#define OUTWORDS (Bd*WORDS)     // 7680

// ---------------------------------------------------------------------------
// K1: pack via global_load_lds (DMA-to-LDS, bypasses L1->VGPR writeback).
// Block stages its 16KB tile: per thread 4x global_load_lds width=16
// (per-lane global src, wave-uniform LDS base + lane*16 -> linear layout).
// After vmcnt(0)+barrier: 16 scalar LDS reads per thread at lane-consecutive
// dwords (conflict-free), each wave-ballot = one finished uint64 word
// (ballot bit l == pixel offset l). Lanes 0..15 store 16 words per wave.
// ---------------------------------------------------------------------------
__global__ __launch_bounds__(256)
void pack_kernel(const float* __restrict__ a, const float* __restrict__ b,
                 uint64_t* __restrict__ packA, uint64_t* __restrict__ packB) {
    __shared__ float tile[PIX_PER_BLOCK];   // 16 KB
    const int blocksA = (Bd * Nn * HW) / PIX_PER_BLOCK;   // 5760
    long long pixBase;
    const float* src; uint64_t* dst;
    if (blockIdx.x < blocksA) {
        src = a; dst = packA;
        pixBase = (long long)blockIdx.x * PIX_PER_BLOCK;
    } else {
        src = b; dst = packB;
        pixBase = (long long)(blockIdx.x - blocksA) * PIX_PER_BLOCK;
    }
    const int t = threadIdx.x, wv = t >> 6, l = t & 63;
    #pragma unroll
    for (int c = 0; c < 4; ++c) {
        const int chunk = wv * 4 + c;                     // 16 chunks x 1KB
        __builtin_amdgcn_global_load_lds(
            (const __attribute__((address_space(1))) unsigned int*)(src + pixBase + chunk * 256 + l * 4),
            (__attribute__((address_space(3))) unsigned int*)(tile + chunk * 256),
            16, 0, 0);
    }
    asm volatile("s_waitcnt vmcnt(0)" ::: "memory");
    __syncthreads();
    uint64_t myw = 0;
    #pragma unroll
    for (int k = 0; k < 16; ++k) {
        float v = tile[t + k * 256];                      // lanes -> consecutive dwords: conflict-free
        uint64_t bal = __ballot(v > 0.0f);                // word for pixels [pixBase + k*256 + wv*64, +64)
        if (l == k) myw = bal;
    }
    if (l < 16)
        dst[(pixBase >> 6) + l * 4 + wv] = myw;           // 16 words/wave, 512B span
}

__device__ __forceinline__ unsigned int wave_sum(unsigned int s) {
    #pragma unroll
    for (int off = 32; off; off >>= 1) s += __shfl_down(s, off);
    return s;
}

// ---------------------------------------------------------------------------
// K2: 2x2-tiled pairwise IoU (unchanged from R8 — measured fast).
// ---------------------------------------------------------------------------
__global__ void pair_kernel(const uint64_t* __restrict__ packA, const uint64_t* __restrict__ packB,
                            unsigned char* __restrict__ q) {
    const int wave = blockIdx.x * 4 + (threadIdx.x >> 6);  // 0..2303
    const int lane = threadIdx.x & 63;
    const int bb = wave / 576;
    const int r  = wave % 576;
    const int ni = (r / 24) * 2, mi = (r % 24) * 2;
    const uint64_t* A0 = packA + ((size_t)bb * Nn + ni) * WORDS;
    const uint64_t* A1 = A0 + WORDS;
    const uint64_t* B0 = packB + ((size_t)bb * Mm + mi) * WORDS;
    const uint64_t* B1 = B0 + WORDS;
    unsigned int i00 = 0, i01 = 0, i10 = 0, i11 = 0, pa0 = 0, pa1 = 0, pb0 = 0, pb1 = 0;
    #pragma unroll 5
    for (int w = lane; w < WORDS; w += 64) {
        uint64_t a0 = A0[w], a1 = A1[w], b0 = B0[w], b1 = B1[w];
        i00 += (unsigned int)__popcll(a0 & b0);
        i01 += (unsigned int)__popcll(a0 & b1);
        i10 += (unsigned int)__popcll(a1 & b0);
        i11 += (unsigned int)__popcll(a1 & b1);
        pa0 += (unsigned int)__popcll(a0);
        pa1 += (unsigned int)__popcll(a1);
        pb0 += (unsigned int)__popcll(b0);
        pb1 += (unsigned int)__popcll(b1);
    }
    i00 = wave_sum(i00); i01 = wave_sum(i01); i10 = wave_sum(i10); i11 = wave_sum(i11);
    pa0 = wave_sum(pa0); pa1 = wave_sum(pa1); pb0 = wave_sum(pb0); pb1 = wave_sum(pb1);
    if (lane == 0) {
        float fa0 = (float)pa0, fa1 = (float)pa1, fb0 = (float)pb0, fb1 = (float)pb1;
        unsigned char q00 = ((float)i00 / fmaxf(fa0 + fb0 - (float)i00, 1.0f)) > 0.8f;
        unsigned char q01 = ((float)i01 / fmaxf(fa0 + fb1 - (float)i01, 1.0f)) > 0.8f;
        unsigned char q10 = ((float)i10 / fmaxf(fa1 + fb0 - (float)i10, 1.0f)) > 0.8f;
        unsigned char q11 = ((float)i11 / fmaxf(fa1 + fb1 - (float)i11, 1.0f)) > 0.8f;
        const size_t base = ((size_t)bb * Nn + ni) * Mm + mi;
        q[base] = q00; q[base + 1] = q01;
        q[base + Mm] = q10; q[base + Mm + 1] = q11;
    }
}

// ---------------------------------------------------------------------------
// K3: zero-words + coalesced float4 expansion (unchanged from R8).
// ---------------------------------------------------------------------------
__global__ void words_expand_kernel(const uint64_t* __restrict__ packA,
                                    const uint64_t* __restrict__ packB,
                                    const unsigned char* __restrict__ q,
                                    float* __restrict__ out) {
    __shared__ uint64_t sw[64];
    __shared__ uint64_t qm[Nn];
    const int t = threadIdx.x;                 // 0..63
    const int base = blockIdx.x * 64;          // global word index base
    const int bb = base / WORDS;
    if (t < Nn) {
        const unsigned int* qrow = reinterpret_cast<const unsigned int*>(q + ((size_t)bb * Nn + t) * Mm);
        uint64_t m = 0;
        #pragma unroll
        for (int k = 0; k < 12; ++k) {
            unsigned int v = qrow[k];          // 4 bytes (0/1) -> 4 bits
            m |= (uint64_t)((v & 1u) | ((v >> 7) & 2u) | ((v >> 14) & 4u) | ((v >> 21) & 8u)) << (4 * k);
        }
        qm[t] = m;
    }
    __syncthreads();
    const int w = (base % WORDS) + t;          // word within this batch's rows
    uint64_t acc = 0;
    for (int n = 0; n < Nn; ++n) {
        uint64_t qmn = qm[n];
        if (!qmn) continue;
        uint64_t aw = packA[((size_t)bb * Nn + n) * WORDS + w];
        while (qmn) {
            int m = __ffsll((long long)qmn) - 1;
            qmn &= qmn - 1;
            acc |= aw ^ packB[((size_t)bb * Mm + m) * WORDS + w];
        }
        if (acc == ~0ull) break;               // word fully covered
    }
    sw[t] = acc;
    __syncthreads();
    float4* out4 = reinterpret_cast<float4*>(out) + (size_t)blockIdx.x * 1024;
    #pragma unroll
    for (int k = 0; k < 16; ++k) {
        int j = k * 64 + t;                    // float4 index within block [0,1024)
        unsigned int bits = (unsigned int)(sw[j >> 4] >> ((4 * j) & 63)) & 0xFu;
        float4 f;
        f.x = (bits & 1u) ? 0.0f : 1.0f;
        f.y = (bits & 2u) ? 0.0f : 1.0f;
        f.z = (bits & 4u) ? 0.0f : 1.0f;
        f.w = (bits & 8u) ? 0.0f : 1.0f;
        out4[j] = f;
    }
}

extern "C" void kernel_launch(void* const* d_in, const int* in_sizes, int n_in,
                              void* d_out, int out_size, void* d_ws, size_t ws_size,
                              hipStream_t stream) {
    const float* a = (const float*)d_in[0];   // stereo_warped_target  [B,N,H,W]
    const float* b = (const float*)d_in[1];   // temporal_warped_target [B,M,H,W]
    float* out = (float*)d_out;               // [B,1,H,W]

    uint8_t* ws = (uint8_t*)d_ws;
    const size_t szPack = (size_t)Bd * Nn * WORDS * sizeof(uint64_t);  // 2.95 MB each
    uint64_t* packA = (uint64_t*)ws;
    uint64_t* packB = (uint64_t*)(ws + szPack);
    unsigned char* q = (unsigned char*)(ws + 2 * szPack);              // 9216 bytes

    // K1: pack via LDS-DMA (11520 blocks)
    pack_kernel<<<(Bd * (Nn + Mm) * HW) / PIX_PER_BLOCK, 256, 0, stream>>>(a, b, packA, packB);

    // K2: 2x2-tiled pair IoU -> q bytes (576 blocks)
    pair_kernel<<<(Bd * 24 * 24) / 4, 256, 0, stream>>>(packA, packB, q);

    // K3: zero-words + float expansion (120 one-wave blocks)
    words_expand_kernel<<<OUTWORDS / 64, 64, 0, stream>>>(packA, packB, q, out);
}